// Round 1
// baseline (226.077 us; speedup 1.0000x reference)
//
#include <hip/hip_runtime.h>

typedef __bf16 bf16;
typedef __bf16 bf16x8 __attribute__((ext_vector_type(8)));
typedef __bf16 bf16x4 __attribute__((ext_vector_type(4)));
typedef float  f32x4  __attribute__((ext_vector_type(4)));

#define NN_  320
#define CZ_  128
#define H_   4
#define CH_  32
// rows total = 320*320 = 102400

// ---------------------------------------------------------------------------
// Kernel 1: QKVG projection.  grid 1600 x 256 threads (4 waves, 16 rows each)
// Q: [n][h][q][32] bf16 (pre-scaled by 1/sqrt(32)); K: [n][h][kv][32];
// V: [n][h][32][kv] (transposed); G: [m][128] = sigmoid(x wg + bg)
// ---------------------------------------------------------------------------
__global__ __launch_bounds__(256) void qkvg_kernel(
    const float* __restrict__ x,
    const float* __restrict__ wq, const float* __restrict__ wk,
    const float* __restrict__ wv, const float* __restrict__ wg,
    const float* __restrict__ bg,
    bf16* __restrict__ Qp, bf16* __restrict__ Kp,
    bf16* __restrict__ Vp, bf16* __restrict__ Gp)
{
    __shared__ bf16 xl[64][136];    // x tile, +8 pad (b128 reads conflict-free)
    __shared__ bf16 wl[128][136];   // transposed weight: wl[j][k]
    const int tid  = threadIdx.x;
    const int lane = tid & 63, wid = tid >> 6;
    const int l15  = lane & 15, l4 = lane >> 4;
    const int m0   = blockIdx.x << 6;

    // stage x tile (fp32 -> bf16), 64 rows x 128 k
    #pragma unroll
    for (int it = 0; it < 8; ++it) {
        int f   = tid + (it << 8);       // float4 unit, 64*32 total
        int row = f >> 5, kq = f & 31;
        float4 v = reinterpret_cast<const float4*>(x + (size_t)(m0 + row) * CZ_)[kq];
        bf16x4 b; b[0] = (bf16)v.x; b[1] = (bf16)v.y; b[2] = (bf16)v.z; b[3] = (bf16)v.w;
        *reinterpret_cast<bf16x4*>(&xl[row][kq << 2]) = b;
    }

    // per-reg row decomposition (D row = wid*16 + l4*4 + r)
    int nn[4], qq[4];
    #pragma unroll
    for (int r = 0; r < 4; ++r) {
        int m = m0 + wid * 16 + l4 * 4 + r;
        nn[r] = m / NN_;
        qq[r] = m - nn[r] * NN_;
    }

    const float* Ws[4] = {wq, wk, wv, wg};

    #pragma unroll
    for (int mat = 0; mat < 4; ++mat) {
        __syncthreads();
        // stage transposed weight wl[j][k] = w[k][j]
        for (int it = 0; it < 64; ++it) {
            int idx = tid + (it << 8);
            wl[idx & 127][idx >> 7] = (bf16)Ws[mat][idx];
        }
        __syncthreads();

        f32x4 zero = {0.f, 0.f, 0.f, 0.f};
        f32x4 acc[8];
        #pragma unroll
        for (int ct = 0; ct < 8; ++ct) acc[ct] = zero;

        #pragma unroll
        for (int ks = 0; ks < 4; ++ks) {
            bf16x8 a = *reinterpret_cast<const bf16x8*>(&xl[wid * 16 + l15][ks * 32 + l4 * 8]);
            #pragma unroll
            for (int ct = 0; ct < 8; ++ct) {
                bf16x8 b = *reinterpret_cast<const bf16x8*>(&wl[ct * 16 + l15][ks * 32 + l4 * 8]);
                acc[ct] = __builtin_amdgcn_mfma_f32_16x16x32_bf16(a, b, acc[ct], 0, 0, 0);
            }
        }

        #pragma unroll
        for (int ct = 0; ct < 8; ++ct) {
            const int j  = ct * 16 + l15;
            const int hh = j >> 5, cc = j & 31;
            float bgj = (mat == 3) ? bg[j] : 0.f;
            #pragma unroll
            for (int r = 0; r < 4; ++r) {
                float v = acc[ct][r];
                if (mat == 0) {
                    Qp[(size_t)((nn[r] * H_ + hh) * NN_ + qq[r]) * CH_ + cc] =
                        (bf16)(v * 0.17677669529663687f);
                } else if (mat == 1) {
                    Kp[(size_t)((nn[r] * H_ + hh) * NN_ + qq[r]) * CH_ + cc] = (bf16)v;
                } else if (mat == 2) {
                    Vp[(size_t)((nn[r] * H_ + hh) * CH_ + cc) * NN_ + qq[r]] = (bf16)v;
                } else {
                    float t = v + bgj;
                    Gp[(size_t)(m0 + wid * 16 + l4 * 4 + r) * CZ_ + j] =
                        (bf16)(1.0f / (1.0f + __expf(-t)));
                }
            }
        }
    }
}

// ---------------------------------------------------------------------------
// Kernel 2: fused attention + gating.  grid (10, 320), 256 threads; wave=head.
// Flash-style online softmax over kv tiles of 32. Overwrites Gp with o*g (bf16).
// ---------------------------------------------------------------------------
__global__ __launch_bounds__(256) void attn_kernel(
    const bf16* __restrict__ Qp, const bf16* __restrict__ Kp,
    const bf16* __restrict__ Vp, bf16* __restrict__ Gp,
    const float* __restrict__ bias)
{
    __shared__ bf16 pl[4][32][40];   // per-wave P tile, row stride 80B (16B-mult)
    const int lane = threadIdx.x & 63;
    const int h    = threadIdx.x >> 6;
    const int n    = blockIdx.y;
    const int q0   = blockIdx.x << 5;
    const int l15  = lane & 15, l4 = lane >> 4;

    const bf16* Qh = Qp + (size_t)(n * H_ + h) * NN_ * CH_;
    const bf16* Kh = Kp + (size_t)(n * H_ + h) * NN_ * CH_;
    const bf16* Vh = Vp + (size_t)(n * H_ + h) * CH_ * NN_;
    const float* bh = bias + ((size_t)h * NN_ + q0) * NN_;

    bf16x8 qf[2];
    qf[0] = *reinterpret_cast<const bf16x8*>(&Qh[(q0 + l15) * CH_ + l4 * 8]);
    qf[1] = *reinterpret_cast<const bf16x8*>(&Qh[(q0 + 16 + l15) * CH_ + l4 * 8]);

    f32x4 zero = {0.f, 0.f, 0.f, 0.f};
    f32x4 o[2][2];
    o[0][0] = zero; o[0][1] = zero; o[1][0] = zero; o[1][1] = zero;
    float mr[2][4], lr[2][4];
    #pragma unroll
    for (int qt = 0; qt < 2; ++qt)
        #pragma unroll
        for (int r = 0; r < 4; ++r) { mr[qt][r] = -1e30f; lr[qt][r] = 0.f; }

    for (int t = 0; t < 10; ++t) {
        const int kv0 = t << 5;
        f32x4 s[2][2];
        {
            bf16x8 kf0 = *reinterpret_cast<const bf16x8*>(&Kh[(kv0 + l15) * CH_ + l4 * 8]);
            bf16x8 kf1 = *reinterpret_cast<const bf16x8*>(&Kh[(kv0 + 16 + l15) * CH_ + l4 * 8]);
            s[0][0] = __builtin_amdgcn_mfma_f32_16x16x32_bf16(qf[0], kf0, zero, 0, 0, 0);
            s[0][1] = __builtin_amdgcn_mfma_f32_16x16x32_bf16(qf[0], kf1, zero, 0, 0, 0);
            s[1][0] = __builtin_amdgcn_mfma_f32_16x16x32_bf16(qf[1], kf0, zero, 0, 0, 0);
            s[1][1] = __builtin_amdgcn_mfma_f32_16x16x32_bf16(qf[1], kf1, zero, 0, 0, 0);
        }
        // bias add (fp32, L2-resident)
        #pragma unroll
        for (int qt = 0; qt < 2; ++qt)
            #pragma unroll
            for (int r = 0; r < 4; ++r) {
                const float* bp = &bh[(size_t)(qt * 16 + l4 * 4 + r) * NN_ + kv0 + l15];
                s[qt][0][r] += bp[0];
                s[qt][1][r] += bp[16];
            }
        // online softmax: row max (16-lane shuffle reduce), rescale
        #pragma unroll
        for (int qt = 0; qt < 2; ++qt)
            #pragma unroll
            for (int r = 0; r < 4; ++r) {
                float v = fmaxf(s[qt][0][r], s[qt][1][r]);
                v = fmaxf(v, __shfl_xor(v, 1));
                v = fmaxf(v, __shfl_xor(v, 2));
                v = fmaxf(v, __shfl_xor(v, 4));
                v = fmaxf(v, __shfl_xor(v, 8));
                float mn = fmaxf(mr[qt][r], v);
                float sc = __expf(mr[qt][r] - mn);
                mr[qt][r] = mn;
                lr[qt][r] *= sc;
                o[qt][0][r] *= sc;
                o[qt][1][r] *= sc;
            }
        // P = exp(s - m), round to bf16, stash in wave-private LDS
        #pragma unroll
        for (int qt = 0; qt < 2; ++qt)
            #pragma unroll
            for (int kt = 0; kt < 2; ++kt)
                #pragma unroll
                for (int r = 0; r < 4; ++r) {
                    float p = __expf(s[qt][kt][r] - mr[qt][r]);
                    bf16 pb = (bf16)p;
                    s[qt][kt][r] = (float)pb;
                    pl[h][qt * 16 + l4 * 4 + r][kt * 16 + l15] = pb;
                }
        // row sums (of the rounded P, for consistency)
        #pragma unroll
        for (int qt = 0; qt < 2; ++qt)
            #pragma unroll
            for (int r = 0; r < 4; ++r) {
                float v = s[qt][0][r] + s[qt][1][r];
                v += __shfl_xor(v, 1);
                v += __shfl_xor(v, 2);
                v += __shfl_xor(v, 4);
                v += __shfl_xor(v, 8);
                lr[qt][r] += v;
            }
        // PV: read P back as A-frags (wave-private LDS; compiler inserts waits)
        #pragma unroll
        for (int qt = 0; qt < 2; ++qt) {
            bf16x8 pf = *reinterpret_cast<const bf16x8*>(&pl[h][qt * 16 + l15][l4 * 8]);
            #pragma unroll
            for (int ct = 0; ct < 2; ++ct) {
                bf16x8 vf = *reinterpret_cast<const bf16x8*>(
                    &Vh[(size_t)(ct * 16 + l15) * NN_ + kv0 + l4 * 8]);
                o[qt][ct] = __builtin_amdgcn_mfma_f32_16x16x32_bf16(pf, vf, o[qt][ct], 0, 0, 0);
            }
        }
    }

    // epilogue: o/l * g, overwrite G with o*g
    #pragma unroll
    for (int qt = 0; qt < 2; ++qt)
        #pragma unroll
        for (int r = 0; r < 4; ++r) {
            float invv = 1.0f / lr[qt][r];
            int q = q0 + qt * 16 + l4 * 4 + r;
            size_t base = ((size_t)(n * NN_ + q)) * CZ_ + h * CH_;
            #pragma unroll
            for (int ct = 0; ct < 2; ++ct) {
                size_t gi = base + ct * 16 + l15;
                float g = (float)Gp[gi];
                Gp[gi] = (bf16)(o[qt][ct][r] * invv * g);
            }
        }
}

// ---------------------------------------------------------------------------
// Kernel 3: out = og @ wo + bo (fp32 out).  grid 1600 x 256 threads.
// ---------------------------------------------------------------------------
__global__ __launch_bounds__(256) void oproj_kernel(
    const bf16* __restrict__ og, const float* __restrict__ wo,
    const float* __restrict__ bo, float* __restrict__ out)
{
    __shared__ bf16 wl[128][136];   // transposed: wl[j][k]
    const int tid  = threadIdx.x;
    const int lane = tid & 63, wid = tid >> 6;
    const int l15  = lane & 15, l4 = lane >> 4;
    const int m0   = blockIdx.x << 6;

    for (int it = 0; it < 64; ++it) {
        int idx = tid + (it << 8);
        wl[idx & 127][idx >> 7] = (bf16)wo[idx];
    }
    __syncthreads();

    f32x4 zero = {0.f, 0.f, 0.f, 0.f};
    f32x4 acc[8];
    #pragma unroll
    for (int ct = 0; ct < 8; ++ct) acc[ct] = zero;

    const int mrow = m0 + wid * 16 + l15;
    #pragma unroll
    for (int ks = 0; ks < 4; ++ks) {
        bf16x8 a = *reinterpret_cast<const bf16x8*>(&og[(size_t)mrow * CZ_ + ks * 32 + l4 * 8]);
        #pragma unroll
        for (int ct = 0; ct < 8; ++ct) {
            bf16x8 b = *reinterpret_cast<const bf16x8*>(&wl[ct * 16 + l15][ks * 32 + l4 * 8]);
            acc[ct] = __builtin_amdgcn_mfma_f32_16x16x32_bf16(a, b, acc[ct], 0, 0, 0);
        }
    }

    #pragma unroll
    for (int ct = 0; ct < 8; ++ct) {
        int cout = ct * 16 + l15;
        float bov = bo[cout];
        #pragma unroll
        for (int r = 0; r < 4; ++r) {
            int m = m0 + wid * 16 + l4 * 4 + r;
            out[(size_t)m * CZ_ + cout] = acc[ct][r] + bov;
        }
    }
}

// ---------------------------------------------------------------------------
extern "C" void kernel_launch(void* const* d_in, const int* in_sizes, int n_in,
                              void* d_out, int out_size, void* d_ws, size_t ws_size,
                              hipStream_t stream) {
    (void)in_sizes; (void)n_in; (void)out_size; (void)ws_size;
    const float* x    = (const float*)d_in[0];
    const float* bias = (const float*)d_in[1];
    const float* wq   = (const float*)d_in[2];
    const float* wk   = (const float*)d_in[3];
    const float* wv   = (const float*)d_in[4];
    const float* wg   = (const float*)d_in[5];
    const float* bg   = (const float*)d_in[6];
    const float* wo   = (const float*)d_in[7];
    const float* bo   = (const float*)d_in[8];
    float* out = (float*)d_out;

    const size_t ELEMS = (size_t)NN_ * NN_ * CZ_;   // 13,107,200
    // ws: Q (26.2MB) + G (26.2MB).  d_out doubles as scratch for K+V (52.4MB,
    // exactly out_size*4 bytes); kernel3 overwrites d_out with the final result.
    bf16* Qp = (bf16*)d_ws;
    bf16* Gp = Qp + ELEMS;
    bf16* Kp = (bf16*)d_out;
    bf16* Vp = Kp + ELEMS;

    qkvg_kernel<<<dim3(1600), 256, 0, stream>>>(x, wq, wk, wv, wg, bg, Qp, Kp, Vp, Gp);
    attn_kernel<<<dim3(10, 320), 256, 0, stream>>>(Qp, Kp, Vp, Gp, bias);
    oproj_kernel<<<dim3(1600), 256, 0, stream>>>(Gp, wo, bo, out);
}